// Round 2
// baseline (110.079 us; speedup 1.0000x reference)
//
#include <hip/hip_runtime.h>

// out = vals[searchsorted(quants[1:], x, left)] for x in (-1e4, 1e4], else x.
// quants = linspace(-1,1,257): quants[k] = -1 + k/128 (exact fp32); vals = relu(quants).
// Closed form: k = clamp(ceil(128x + 128) - 1, 0, 256); out = max(k/128 - 1, 0).
// Memory-bound streaming elementwise:
//   - float4 (16B/lane) accesses
//   - 4x unrolled independent loads per thread for MLP/ILP
//   - non-temporal load/store (data touched exactly once; skip cache pollution)
//   - grid-stride, 2048 blocks x 256 = 8192 waves = full CU wave capacity

typedef float f4 __attribute__((ext_vector_type(4)));

__device__ __forceinline__ f4 proc4(f4 v) {
    f4 r;
#pragma unroll
    for (int j = 0; j < 4; ++j) {
        float x = v[j];
        float t = fmaf(x, 128.0f, 128.0f);           // 128*(x+1), single rounding
        int k = (int)ceilf(t) - 1;                   // searchsorted-left bucket
        k = k < 0 ? 0 : (k > 256 ? 256 : k);
        float y = fmaxf(fmaf((float)k, 0.0078125f, -1.0f), 0.0f);  // relu(quants[k])
        // guard: outside (-1e4, 1e4] (and NaN) passes through unchanged
        r[j] = (x > -10000.0f && x <= 10000.0f) ? y : x;
    }
    return r;
}

__global__ void __launch_bounds__(256) quant_relu_kernel(
    const f4* __restrict__ in, f4* __restrict__ out, int n4) {
    const int gid = blockIdx.x * blockDim.x + threadIdx.x;
    const int stride = gridDim.x * blockDim.x;

    int i = gid;
    // main loop: 4 independent 16B loads in flight per iteration
    for (; i + 3 * stride < n4; i += 4 * stride) {
        f4 v0 = __builtin_nontemporal_load(&in[i]);
        f4 v1 = __builtin_nontemporal_load(&in[i + stride]);
        f4 v2 = __builtin_nontemporal_load(&in[i + 2 * stride]);
        f4 v3 = __builtin_nontemporal_load(&in[i + 3 * stride]);
        __builtin_nontemporal_store(proc4(v0), &out[i]);
        __builtin_nontemporal_store(proc4(v1), &out[i + stride]);
        __builtin_nontemporal_store(proc4(v2), &out[i + 2 * stride]);
        __builtin_nontemporal_store(proc4(v3), &out[i + 3 * stride]);
    }
    // remainder
    for (; i < n4; i += stride) {
        f4 v = __builtin_nontemporal_load(&in[i]);
        __builtin_nontemporal_store(proc4(v), &out[i]);
    }
}

// scalar tail handler (n % 4 != 0; not hit for 64M but stay general)
__global__ void quant_relu_tail(const float* __restrict__ in, float* __restrict__ out,
                                int n_start, int n) {
    int i = n_start + blockIdx.x * blockDim.x + threadIdx.x;
    if (i < n) {
        float x = in[i];
        float t = fmaf(x, 128.0f, 128.0f);
        int k = (int)ceilf(t) - 1;
        k = k < 0 ? 0 : (k > 256 ? 256 : k);
        float y = fmaxf(fmaf((float)k, 0.0078125f, -1.0f), 0.0f);
        out[i] = (x > -10000.0f && x <= 10000.0f) ? y : x;
    }
}

extern "C" void kernel_launch(void* const* d_in, const int* in_sizes, int n_in,
                              void* d_out, int out_size, void* d_ws, size_t ws_size,
                              hipStream_t stream) {
    const float* x = (const float*)d_in[0];   // 64*1024*1024 fp32
    float* out = (float*)d_out;

    const int n = in_sizes[0];
    const int n4 = n >> 2;
    const int tail = n & 3;

    const int block = 256;
    int grid = (n4 + block - 1) / block;
    if (grid > 2048) grid = 2048;
    if (grid < 1) grid = 1;

    quant_relu_kernel<<<grid, block, 0, stream>>>((const f4*)x, (f4*)out, n4);

    if (tail) {
        quant_relu_tail<<<1, 64, 0, stream>>>(x, out, n4 * 4, n);
    }
}

// Round 3
// 91.603 us; speedup vs baseline: 1.2017x; 1.2017x over previous
//
#include <hip/hip_runtime.h>

// out = vals[searchsorted(quants[1:], x, left)] for x in (-1e4, 1e4], else x.
// quants = linspace(-1,1,257): quants[k] = -1 + k/128 (exact fp32); vals = relu(quants).
// Closed form: k = clamp(ceil(128x + 128) - 1, 0, 256); out = max(k/128 - 1, 0).
//
// Memory-bound streaming elementwise. Round-3 structure: FLAT kernel, one
// float4 per thread (no grid-stride loop). Rationale: in a loop, the
// compiler's s_waitcnt before each load-use also drains the previous
// iteration's stores (vmcnt counts both), serializing on store retirement.
// A flat kernel issues load->compute->store->endpgm; waves retire and the
// dispatcher refills the CU, so stores never gate loads. Plain (cached)
// loads/stores: nt regressed round 2.

typedef float f4 __attribute__((ext_vector_type(4)));

__device__ __forceinline__ f4 proc4(f4 v) {
    f4 r;
#pragma unroll
    for (int j = 0; j < 4; ++j) {
        float x = v[j];
        float t = fmaf(x, 128.0f, 128.0f);           // 128*(x+1), single rounding
        int k = (int)ceilf(t) - 1;                   // searchsorted-left bucket
        k = k < 0 ? 0 : (k > 256 ? 256 : k);
        float y = fmaxf(fmaf((float)k, 0.0078125f, -1.0f), 0.0f);  // relu(quants[k])
        // guard: outside (-1e4, 1e4] (and NaN) passes through unchanged
        r[j] = (x > -10000.0f && x <= 10000.0f) ? y : x;
    }
    return r;
}

__global__ void __launch_bounds__(256) quant_relu_flat(
    const f4* __restrict__ in, f4* __restrict__ out, int n4) {
    const int i = blockIdx.x * blockDim.x + threadIdx.x;
    if (i < n4) {
        out[i] = proc4(in[i]);
    }
}

// scalar tail handler (n % 4 != 0; not hit for 64M but stay general)
__global__ void quant_relu_tail(const float* __restrict__ in, float* __restrict__ out,
                                int n_start, int n) {
    int i = n_start + blockIdx.x * blockDim.x + threadIdx.x;
    if (i < n) {
        float x = in[i];
        float t = fmaf(x, 128.0f, 128.0f);
        int k = (int)ceilf(t) - 1;
        k = k < 0 ? 0 : (k > 256 ? 256 : k);
        float y = fmaxf(fmaf((float)k, 0.0078125f, -1.0f), 0.0f);
        out[i] = (x > -10000.0f && x <= 10000.0f) ? y : x;
    }
}

extern "C" void kernel_launch(void* const* d_in, const int* in_sizes, int n_in,
                              void* d_out, int out_size, void* d_ws, size_t ws_size,
                              hipStream_t stream) {
    const float* x = (const float*)d_in[0];   // 64*1024*1024 fp32
    float* out = (float*)d_out;

    const int n = in_sizes[0];
    const int n4 = n >> 2;
    const int tail = n & 3;

    const int block = 256;
    const int grid = (n4 + block - 1) / block;   // 65536 blocks for 64M elements

    if (grid > 0) {
        quant_relu_flat<<<grid, block, 0, stream>>>((const f4*)x, (f4*)out, n4);
    }
    if (tail) {
        quant_relu_tail<<<1, 64, 0, stream>>>(x, out, n4 * 4, n);
    }
}